// Round 4
// baseline (189.676 us; speedup 1.0000x reference)
//
#include <hip/hip_runtime.h>

// DCT_18769007084406: RGB->YCbCr (1x1 conv) -> 8x8 stride-8 block DCT
// (grouped conv) -> 32x repeated (t-min)/d normalization (closed form).
//
// R4: occupancy-first. One 256-thread block per (b, block-row) band,
// grid 2048. Stage 0: 12 dense independent float4 loads/thread (full MLP),
// YCbCr in-place in registers (48 parked VGPRs). Then 3 channel rounds
// against a single 16 KB LDS buffer: write channel -> barrier -> DCT.
// Stage 2: wave w owns u in {2w, 2w+1} (wave-uniform -> BASIS rows become
// immediates via template), lane = block-col -> 256B coalesced stores.
// __launch_bounds__(256,5): <=102 VGPR -> 5 blocks/CU = 20 waves/CU.

#define HW 512
#define CHST (HW * HW)       // channel stride in x (floats)
#define NPAIR 6144           // 32 * 192 (b, out-channel) pairs
#define EPS 1e-6f

// basis[u][i] = c(u) * cos(pi*u*(i+0.5)/8); c(0)=sqrt(1/8), c(u>0)=0.5
static constexpr float BASIS[8][8] = {
  { 0.35355339059327373f, 0.35355339059327373f, 0.35355339059327373f, 0.35355339059327373f,
    0.35355339059327373f, 0.35355339059327373f, 0.35355339059327373f, 0.35355339059327373f },
  { 0.49039264020161522f, 0.41573480615127262f, 0.27778511650980114f, 0.09754516100806412f,
   -0.09754516100806412f,-0.27778511650980114f,-0.41573480615127262f,-0.49039264020161522f },
  { 0.46193976625564337f, 0.19134171618254492f,-0.19134171618254492f,-0.46193976625564337f,
   -0.46193976625564337f,-0.19134171618254492f, 0.19134171618254492f, 0.46193976625564337f },
  { 0.41573480615127262f,-0.09754516100806412f,-0.49039264020161522f,-0.27778511650980114f,
    0.27778511650980114f, 0.49039264020161522f, 0.09754516100806412f,-0.41573480615127262f },
  { 0.35355339059327373f,-0.35355339059327373f,-0.35355339059327373f, 0.35355339059327373f,
    0.35355339059327373f,-0.35355339059327373f,-0.35355339059327373f, 0.35355339059327373f },
  { 0.27778511650980114f,-0.49039264020161522f, 0.09754516100806412f, 0.41573480615127262f,
   -0.41573480615127262f,-0.09754516100806412f, 0.49039264020161522f,-0.27778511650980114f },
  { 0.19134171618254492f,-0.46193976625564337f, 0.46193976625564337f,-0.19134171618254492f,
   -0.19134171618254492f, 0.46193976625564337f,-0.46193976625564337f, 0.19134171618254492f },
  { 0.09754516100806412f,-0.27778511650980114f, 0.41573480615127262f,-0.49039264020161522f,
    0.49039264020161522f,-0.41573480615127262f, 0.27778511650980114f,-0.09754516100806412f }
};

// t_32 = a^32 * t0 - min * sum_{k=1..32} a^k, a = 1/(max-min+eps)
__global__ void precomp_norm(const float* __restrict__ max_,
                             const float* __restrict__ min_,
                             float* __restrict__ so) {
    int i = blockIdx.x * 256 + threadIdx.x;
    if (i >= NPAIR) return;
    float mn = min_[i], mx = max_[i];
    float d = mx - mn + EPS;
    float a = 1.0f / d;
    float a2 = a * a, a4 = a2 * a2, a8 = a4 * a4, a16 = a8 * a8, a32 = a16 * a16;
    float geo = a * (1.0f - a32) / (1.0f - a);   // sum_{k=1..32} a^k
    so[2 * i]     = a32;
    so[2 * i + 1] = -mn * geo;
}

// Col-DCT + norm + store for wave-uniform u pair {U0, U0+1}.
template <int U0, bool USE_WS>
__device__ __forceinline__
void dct_cols(const float* __restrict__ ylds, int lane, int obase, int by,
              const float* __restrict__ so, const float* __restrict__ max_,
              const float* __restrict__ min_, float* __restrict__ out) {
    const float* yb = ylds + lane * 8;
    float t0[8], t1[8];
#pragma unroll
    for (int j = 0; j < 8; ++j) { t0[j] = 0.0f; t1[j] = 0.0f; }

#pragma unroll
    for (int i = 0; i < 8; ++i) {
        float yv[8];
        *(float4*)(&yv[0]) = *(const float4*)(yb + i * HW);
        *(float4*)(&yv[4]) = *(const float4*)(yb + i * HW + 4);
        const float b0 = BASIS[U0][i];
        const float b1 = BASIS[U0 + 1][i];
#pragma unroll
        for (int j = 0; j < 8; ++j) {
            t0[j] = fmaf(b0, yv[j], t0[j]);
            t1[j] = fmaf(b1, yv[j], t1[j]);
        }
    }

    float* op = out + ((size_t)obase * 64 + by) * 64 + lane;

    auto colpass = [&](const float (&tp)[8], int u) {
#pragma unroll
        for (int v = 0; v < 8; ++v) {
            float acc = tp[0] * BASIS[v][0];
#pragma unroll
            for (int j = 1; j < 8; ++j)
                acc = fmaf(tp[j], BASIS[v][j], acc);
            const int k = u * 8 + v;          // wave-uniform
            float s, o;
            if (USE_WS) {
                s = so[(obase + k) * 2];
                o = so[(obase + k) * 2 + 1];
            } else {
                float mn = min_[obase + k], mx = max_[obase + k];
                float d  = mx - mn + EPS;
                float a  = 1.0f / d;
                float a2 = a * a, a4 = a2 * a2, a8 = a4 * a4, a16 = a8 * a8, a32 = a16 * a16;
                s = a32;
                o = -mn * (a * (1.0f - a32) / (1.0f - a));
            }
            op[(size_t)k * 4096] = fmaf(s, acc, o);   // 256B coalesced in lane
        }
    };
    colpass(t0, U0);
    colpass(t1, U0 + 1);
}

template <bool USE_WS>
__global__ __launch_bounds__(256, 5)
void dct_kernel(const float* __restrict__ x,
                const float* __restrict__ ycbcr_w,
                const float* __restrict__ so,
                const float* __restrict__ max_,
                const float* __restrict__ min_,
                float* __restrict__ out) {
    __shared__ float ylds[8 * HW];   // one channel band: 16 KB

    const int b    = blockIdx.x >> 6;     // batch
    const int by   = blockIdx.x & 63;     // block-row
    const int t    = threadIdx.x;
    const int wv   = t >> 6;              // wave id -> u pair
    const int lane = t & 63;              // lane = block-col

    // ---- stage 0: dense band load (12 independent float4s), YCbCr in-place
    const float* band = x + (size_t)(b * 3) * CHST + (size_t)(by * 8) * HW;

    float4 Yv[4], Cbv[4], Crv[4];
#pragma unroll
    for (int q = 0; q < 4; ++q) {
        const int o = t + 256 * q;
        Yv[q]  = ((const float4*)(band))[o];
        Cbv[q] = ((const float4*)(band + CHST))[o];
        Crv[q] = ((const float4*)(band + 2 * CHST))[o];
    }
    const float w00 = ycbcr_w[0], w01 = ycbcr_w[1], w02 = ycbcr_w[2];
    const float w10 = ycbcr_w[3], w11 = ycbcr_w[4], w12 = ycbcr_w[5];
    const float w20 = ycbcr_w[6], w21 = ycbcr_w[7], w22 = ycbcr_w[8];
#pragma unroll
    for (int q = 0; q < 4; ++q) {
        const float4 r = Yv[q], g = Cbv[q], bb = Crv[q];
        float4 y, cb, cr;
        y.x  = fmaf(w00, r.x, fmaf(w01, g.x, w02 * bb.x));
        y.y  = fmaf(w00, r.y, fmaf(w01, g.y, w02 * bb.y));
        y.z  = fmaf(w00, r.z, fmaf(w01, g.z, w02 * bb.z));
        y.w  = fmaf(w00, r.w, fmaf(w01, g.w, w02 * bb.w));
        cb.x = fmaf(w10, r.x, fmaf(w11, g.x, w12 * bb.x));
        cb.y = fmaf(w10, r.y, fmaf(w11, g.y, w12 * bb.y));
        cb.z = fmaf(w10, r.z, fmaf(w11, g.z, w12 * bb.z));
        cb.w = fmaf(w10, r.w, fmaf(w11, g.w, w12 * bb.w));
        cr.x = fmaf(w20, r.x, fmaf(w21, g.x, w22 * bb.x));
        cr.y = fmaf(w20, r.y, fmaf(w21, g.y, w22 * bb.y));
        cr.z = fmaf(w20, r.z, fmaf(w21, g.z, w22 * bb.z));
        cr.w = fmaf(w20, r.w, fmaf(w21, g.w, w22 * bb.w));
        Yv[q] = y; Cbv[q] = cb; Crv[q] = cr;
    }

    // ---- 3 channel rounds: LDS write -> barrier -> DCT -> barrier
    float4* yv4 = (float4*)ylds;

    auto round = [&](const float4 (&V)[4], int c, bool last) {
#pragma unroll
        for (int q = 0; q < 4; ++q) yv4[t + 256 * q] = V[q];
        __syncthreads();
        const int obase = b * 192 + c * 64;
        switch (wv) {
            case 0: dct_cols<0, USE_WS>(ylds, lane, obase, by, so, max_, min_, out); break;
            case 1: dct_cols<2, USE_WS>(ylds, lane, obase, by, so, max_, min_, out); break;
            case 2: dct_cols<4, USE_WS>(ylds, lane, obase, by, so, max_, min_, out); break;
            default: dct_cols<6, USE_WS>(ylds, lane, obase, by, so, max_, min_, out); break;
        }
        if (!last) __syncthreads();   // guard LDS reuse by next round
    };

    round(Yv,  0, false);
    round(Cbv, 1, false);
    round(Crv, 2, true);
}

extern "C" void kernel_launch(void* const* d_in, const int* in_sizes, int n_in,
                              void* d_out, int out_size, void* d_ws, size_t ws_size,
                              hipStream_t stream) {
    const float* x    = (const float*)d_in[0];
    const float* max_ = (const float*)d_in[1];
    const float* min_ = (const float*)d_in[2];
    const float* yw   = (const float*)d_in[3];
    float* out = (float*)d_out;
    float* so  = (float*)d_ws;

    const bool use_ws = (ws_size >= (size_t)NPAIR * 2 * sizeof(float));
    if (use_ws) {
        precomp_norm<<<(NPAIR + 255) / 256, 256, 0, stream>>>(max_, min_, so);
        dct_kernel<true><<<32 * 64, 256, 0, stream>>>(x, yw, so, max_, min_, out);
    } else {
        dct_kernel<false><<<32 * 64, 256, 0, stream>>>(x, yw, nullptr, max_, min_, out);
    }
}